// Round 1
// baseline (229.289 us; speedup 1.0000x reference)
//
#include <hip/hip_runtime.h>
#include <hip/hip_bf16.h>
#include <cstdint>
#include <cstddef>

#define T_TOK 2048
#define HDIM  1024
#define FDIM  2048
#define NEXP  8

#define BM 128
#define BN 64
#define BK 32
#define LDA 40              // padded LDS leading dim (bf16 elems): 80B rows -> 2-way-free banking
#define MT1 (T_TOK / BM)    // 16 m-tiles (worst case)
#define NT1 (FDIM / BN)     // 32 n-tiles (gate/up)
#define NT2 (HDIM / BN)     // 16 n-tiles (down)

typedef __attribute__((ext_vector_type(8))) short bf16x8;
typedef __attribute__((ext_vector_type(4))) float f32x4;

__device__ __forceinline__ unsigned short f2b(float f) {
  __hip_bfloat16 h = __float2bfloat16(f);
  return __builtin_bit_cast(unsigned short, h);
}

// ---------------- router + sparsemixer (eval) + x->bf16 ----------------
__global__ __launch_bounds__(256) void router_k(
    const float* __restrict__ x, const float* __restrict__ rw,
    float* __restrict__ wslot, int* __restrict__ rows,
    int* __restrict__ cnt, unsigned short* __restrict__ xb)
{
  const int wave = threadIdx.x >> 6, lane = threadIdx.x & 63;
  const int t = blockIdx.x * 4 + wave;
  const float* xr = x + (size_t)t * HDIM;
  unsigned short* xbr = xb + (size_t)t * HDIM;
  float acc[NEXP];
#pragma unroll
  for (int e = 0; e < NEXP; ++e) acc[e] = 0.f;
  for (int i = 0; i < HDIM / 64; ++i) {
    const int h = i * 64 + lane;
    const float xv = xr[h];
    xbr[h] = f2b(xv);
#pragma unroll
    for (int e = 0; e < NEXP; ++e) acc[e] += xv * rw[e * HDIM + h];
  }
#pragma unroll
  for (int e = 0; e < NEXP; ++e) {
#pragma unroll
    for (int off = 32; off; off >>= 1) acc[e] += __shfl_xor(acc[e], off);
  }
  if (lane == 0) {
    // ---- top-1 round ----
    float m1 = acc[0]; int i1 = 0;
#pragma unroll
    for (int e = 1; e < NEXP; ++e) if (acc[e] > m1) { m1 = acc[e]; i1 = e; }
    float sum1 = 0.f;
#pragma unroll
    for (int e = 0; e < NEXP; ++e) {
      const float f = fmaxf(fabsf(acc[e]), m1);
      if (m1 - acc[e] <= 0.02f * f) sum1 += expf(acc[e] - m1);   // unmasked
    }
    // ---- top-2 round (top-1 masked to -inf) ----
    float m2 = -3.4e38f; int i2 = 0;
#pragma unroll
    for (int e = 0; e < NEXP; ++e)
      if (e != i1 && acc[e] > m2) { m2 = acc[e]; i2 = e; }
    float sum2 = 0.f;
#pragma unroll
    for (int e = 0; e < NEXP; ++e) {
      if (e == i1) continue;
      const float f = fmaxf(fabsf(acc[e]), m2);
      if (m2 - acc[e] <= 0.02f * f) sum2 += expf(acc[e] - m2);
    }
    wslot[2 * t]     = 1.f / sum1;   // gate of argmax element = exp(0)/sum
    wslot[2 * t + 1] = 1.f / sum2;
    int p1 = atomicAdd(&cnt[i1], 1); rows[i1 * T_TOK + p1] = 2 * t;
    int p2 = atomicAdd(&cnt[i2], 1); rows[i2 * T_TOK + p2] = 2 * t + 1;
  }
}

// ---------------- gate/up GEMM: h = silu(x Wg^T) * (x Wu^T) * w ----------------
__global__ __launch_bounds__(256) void gemm_gateup_k(
    const unsigned short* __restrict__ xb, const float* __restrict__ wg,
    const float* __restrict__ wu, const int* __restrict__ rows,
    const int* __restrict__ cnt, const float* __restrict__ wslot,
    unsigned short* __restrict__ hbuf)
{
  const int bx = blockIdx.x;
  const int e  = bx >> 9;          // / (MT1*NT1=512)
  const int rm = bx & 511;
  const int mt = rm >> 5;          // / NT1
  const int nt = rm & 31;
  const int cnt_e = cnt[e];
  if (mt * BM >= cnt_e) return;

  __shared__ unsigned short As[BM * LDA];
  __shared__ unsigned short Bg[BN * LDA];
  __shared__ unsigned short Bu[BN * LDA];
  __shared__ int ldsRow[BM];

  const int tid = threadIdx.x;
  if (tid < BM) {
    const int idx = mt * BM + tid;
    ldsRow[tid] = (idx < cnt_e) ? rows[e * T_TOK + idx] : -1;
  }
  __syncthreads();

  const int lane = tid & 63, w = tid >> 6;
  const int wr = w >> 1, wc = w & 1;        // 2x2 wave grid: 64x32 per wave
  const int lr = lane & 15, lq = lane >> 4;

  f32x4 accg[4][2], accu[4][2];
#pragma unroll
  for (int mf = 0; mf < 4; ++mf)
#pragma unroll
    for (int nf = 0; nf < 2; ++nf) {
      accg[mf][nf] = (f32x4){0.f, 0.f, 0.f, 0.f};
      accu[mf][nf] = (f32x4){0.f, 0.f, 0.f, 0.f};
    }

  const float* wgE = wg + ((size_t)e * FDIM + nt * BN) * HDIM;
  const float* wuE = wu + ((size_t)e * FDIM + nt * BN) * HDIM;

  const int srow = tid >> 2;           // 0..63
  const int sko  = (tid & 3) * 8;      // bf16 k-offset {0,8,16,24}

  for (int k0 = 0; k0 < HDIM; k0 += BK) {
    // stage A (gathered bf16 x rows): 128 rows x 32 k
#pragma unroll
    for (int it = 0; it < 2; ++it) {
      const int row = it * 64 + srow;
      const int r = ldsRow[row];
      uint4 v = {0u, 0u, 0u, 0u};
      if (r >= 0)
        v = *(const uint4*)(xb + (size_t)(r >> 1) * HDIM + k0 + sko);
      *(uint4*)(&As[row * LDA + sko]) = v;
    }
    // stage Bg, Bu (fp32 -> bf16): 64 rows x 32 k each
    {
      const float* src = wgE + (size_t)srow * HDIM + k0 + sko;
      const float4 f0 = *(const float4*)src;
      const float4 f1 = *(const float4*)(src + 4);
      union { unsigned short s[8]; uint4 v; } p;
      p.s[0] = f2b(f0.x); p.s[1] = f2b(f0.y); p.s[2] = f2b(f0.z); p.s[3] = f2b(f0.w);
      p.s[4] = f2b(f1.x); p.s[5] = f2b(f1.y); p.s[6] = f2b(f1.z); p.s[7] = f2b(f1.w);
      *(uint4*)(&Bg[srow * LDA + sko]) = p.v;
    }
    {
      const float* src = wuE + (size_t)srow * HDIM + k0 + sko;
      const float4 f0 = *(const float4*)src;
      const float4 f1 = *(const float4*)(src + 4);
      union { unsigned short s[8]; uint4 v; } p;
      p.s[0] = f2b(f0.x); p.s[1] = f2b(f0.y); p.s[2] = f2b(f0.z); p.s[3] = f2b(f0.w);
      p.s[4] = f2b(f1.x); p.s[5] = f2b(f1.y); p.s[6] = f2b(f1.z); p.s[7] = f2b(f1.w);
      *(uint4*)(&Bu[srow * LDA + sko]) = p.v;
    }
    __syncthreads();

    bf16x8 a[4], bg[2], bu[2];
#pragma unroll
    for (int mf = 0; mf < 4; ++mf)
      a[mf] = *(const bf16x8*)&As[(wr * 64 + mf * 16 + lr) * LDA + lq * 8];
#pragma unroll
    for (int nf = 0; nf < 2; ++nf) {
      bg[nf] = *(const bf16x8*)&Bg[(wc * 32 + nf * 16 + lr) * LDA + lq * 8];
      bu[nf] = *(const bf16x8*)&Bu[(wc * 32 + nf * 16 + lr) * LDA + lq * 8];
    }
#pragma unroll
    for (int mf = 0; mf < 4; ++mf)
#pragma unroll
      for (int nf = 0; nf < 2; ++nf) {
        accg[mf][nf] = __builtin_amdgcn_mfma_f32_16x16x32_bf16(a[mf], bg[nf], accg[mf][nf], 0, 0, 0);
        accu[mf][nf] = __builtin_amdgcn_mfma_f32_16x16x32_bf16(a[mf], bu[nf], accu[mf][nf], 0, 0, 0);
      }
    __syncthreads();
  }

  // epilogue: h = silu(g)*u*w  (C/D frag: col=lane&15, row=(lane>>4)*4+i)
#pragma unroll
  for (int mf = 0; mf < 4; ++mf)
#pragma unroll
    for (int nf = 0; nf < 2; ++nf) {
      const int col = nt * BN + wc * 32 + nf * 16 + lr;
#pragma unroll
      for (int i = 0; i < 4; ++i) {
        const int lrow = wr * 64 + mf * 16 + lq * 4 + i;
        const int r = ldsRow[lrow];
        if (r < 0) continue;
        const float g = accg[mf][nf][i], u = accu[mf][nf][i];
        const float val = g / (1.f + __expf(-g)) * u * wslot[r];
        hbuf[(size_t)r * FDIM + col] = f2b(val);
      }
    }
}

// ---------------- down GEMM: out[t] += h Wd^T ----------------
__global__ __launch_bounds__(256) void gemm_down_k(
    const unsigned short* __restrict__ hbuf, const float* __restrict__ wd,
    const int* __restrict__ rows, const int* __restrict__ cnt,
    float* __restrict__ out)
{
  const int bx = blockIdx.x;
  const int e  = bx >> 8;          // / (MT1*NT2=256)
  const int rm = bx & 255;
  const int mt = rm >> 4;          // / NT2
  const int nt = rm & 15;
  const int cnt_e = cnt[e];
  if (mt * BM >= cnt_e) return;

  __shared__ unsigned short As[BM * LDA];
  __shared__ unsigned short Bs[BN * LDA];
  __shared__ int ldsRow[BM];

  const int tid = threadIdx.x;
  if (tid < BM) {
    const int idx = mt * BM + tid;
    ldsRow[tid] = (idx < cnt_e) ? rows[e * T_TOK + idx] : -1;
  }
  __syncthreads();

  const int lane = tid & 63, w = tid >> 6;
  const int wr = w >> 1, wc = w & 1;
  const int lr = lane & 15, lq = lane >> 4;

  f32x4 acc[4][2];
#pragma unroll
  for (int mf = 0; mf < 4; ++mf)
#pragma unroll
    for (int nf = 0; nf < 2; ++nf) acc[mf][nf] = (f32x4){0.f, 0.f, 0.f, 0.f};

  const float* wdE = wd + ((size_t)e * HDIM + nt * BN) * FDIM;

  const int srow = tid >> 2;
  const int sko  = (tid & 3) * 8;

  for (int k0 = 0; k0 < FDIM; k0 += BK) {
#pragma unroll
    for (int it = 0; it < 2; ++it) {
      const int row = it * 64 + srow;
      const int r = ldsRow[row];
      uint4 v = {0u, 0u, 0u, 0u};
      if (r >= 0)
        v = *(const uint4*)(hbuf + (size_t)r * FDIM + k0 + sko);
      *(uint4*)(&As[row * LDA + sko]) = v;
    }
    {
      const float* src = wdE + (size_t)srow * FDIM + k0 + sko;
      const float4 f0 = *(const float4*)src;
      const float4 f1 = *(const float4*)(src + 4);
      union { unsigned short s[8]; uint4 v; } p;
      p.s[0] = f2b(f0.x); p.s[1] = f2b(f0.y); p.s[2] = f2b(f0.z); p.s[3] = f2b(f0.w);
      p.s[4] = f2b(f1.x); p.s[5] = f2b(f1.y); p.s[6] = f2b(f1.z); p.s[7] = f2b(f1.w);
      *(uint4*)(&Bs[srow * LDA + sko]) = p.v;
    }
    __syncthreads();

    bf16x8 a[4], b[2];
#pragma unroll
    for (int mf = 0; mf < 4; ++mf)
      a[mf] = *(const bf16x8*)&As[(wr * 64 + mf * 16 + lr) * LDA + lq * 8];
#pragma unroll
    for (int nf = 0; nf < 2; ++nf)
      b[nf] = *(const bf16x8*)&Bs[(wc * 32 + nf * 16 + lr) * LDA + lq * 8];
#pragma unroll
    for (int mf = 0; mf < 4; ++mf)
#pragma unroll
      for (int nf = 0; nf < 2; ++nf)
        acc[mf][nf] = __builtin_amdgcn_mfma_f32_16x16x32_bf16(a[mf], b[nf], acc[mf][nf], 0, 0, 0);
    __syncthreads();
  }

#pragma unroll
  for (int mf = 0; mf < 4; ++mf)
#pragma unroll
    for (int nf = 0; nf < 2; ++nf) {
      const int col = nt * BN + wc * 32 + nf * 16 + lr;
#pragma unroll
      for (int i = 0; i < 4; ++i) {
        const int lrow = wr * 64 + mf * 16 + lq * 4 + i;
        const int r = ldsRow[lrow];
        if (r < 0) continue;
        atomicAdd(&out[(size_t)(r >> 1) * HDIM + col], acc[mf][nf][i]);
      }
    }
}

extern "C" void kernel_launch(void* const* d_in, const int* in_sizes, int n_in,
                              void* d_out, int out_size, void* d_ws, size_t ws_size,
                              hipStream_t stream) {
  const float* x  = (const float*)d_in[0];   // [2,1024,1024]
  const float* rw = (const float*)d_in[1];   // [8,1024]
  const float* wg = (const float*)d_in[2];   // [8,2048,1024]
  const float* wu = (const float*)d_in[3];   // [8,2048,1024]
  const float* wd = (const float*)d_in[4];   // [8,1024,2048]
  float* out = (float*)d_out;

  char* ws = (char*)d_ws;
  unsigned short* hbuf = (unsigned short*)ws;                       // 4096*2048*2 = 16 MiB
  int*   cnt   = (int*)  (ws + (16u << 20));                        // 8 ints (padded 256B)
  int*   rows  = (int*)  (ws + (16u << 20) + 256);                  // 8*2048*4 = 64 KiB
  float* wslot = (float*)(ws + (16u << 20) + 256 + 65536);          // 4096*4 = 16 KiB
  unsigned short* xb = (unsigned short*)(ws + (17u << 20));         // 2048*1024*2 = 4 MiB

  hipMemsetAsync(cnt, 0, 256, stream);
  hipMemsetAsync(out, 0, (size_t)T_TOK * HDIM * sizeof(float), stream);
  router_k<<<T_TOK / 4, 256, 0, stream>>>(x, rw, wslot, rows, cnt, xb);
  gemm_gateup_k<<<NEXP * MT1 * NT1, 256, 0, stream>>>(xb, wg, wu, rows, cnt, wslot, hbuf);
  gemm_down_k<<<NEXP * MT1 * NT2, 256, 0, stream>>>(hbuf, wd, rows, cnt, out);
}